// Round 11
// baseline (168.206 us; speedup 1.0000x reference)
//
#include <hip/hip_runtime.h>
#include <stdint.h>

typedef unsigned long long u64;

#define NB 2
#define N_ANCHORS 262144           // 2^18
#define PRE_NMS 6000
#define PROPOSALS 2000
#define NCHUNK 94                  // ceil(6000/64) words in keep/suppress bitset
#define CAND_CAP 8192
#define HBINS 16384                // scores in (0,1) -> key>>16 <= 0x3F80 < 16384
#define HB_BLOCKS_PER_B 32
#define HB_CHUNK (N_ANCHORS / HB_BLOCKS_PER_B)   // 8192
#define HR_BLOCKS_PER_B 16         // reduce blocks per batch (1024 bins each)
#define CB_BLOCKS_PER_B 64
#define CB_CHUNK (N_ANCHORS / CB_BLOCKS_PER_B)   // 4096
#define CBUF 512
#define WINDOW 2048                // candidate bins span ~17 bins here; 2048 is ample
#define EDGE_CAP 65536
#define EBUF 2048                  // per-block LDS edge buffer (expected total ~600)
#define IOU_BLOCKS_PER_B NCHUNK    // 94 column-owner blocks per batch

// ---- workspace layout (bytes) ---- no pre-zero kernel: hrows/hist/suff fully
// overwritten; done-counters zeroed by K1; binCnt+edgeCnt zeroed by K2-lastblock;
// cand guarded by totalCand; boxes ranks [0,6000) all written; edges by edgeCount.
#define OFF_HIST 0                                  // 131072
#define OFF_BCNT (NB*HBINS*4)                       // 131072
#define OFF_SCAL (2*NB*HBINS*4)                     // 256
#define OFF_CAND (OFF_SCAL + 256)                   // 131072
#define OFF_SUFF (OFF_CAND + NB*CAND_CAP*8)         // 131072
#define OFF_BOXES (OFF_SUFF + NB*HBINS*4)           // 192000
#define OFF_EDGES (OFF_BOXES + NB*PRE_NMS*16)       // 524288
#define OFF_HROWS (OFF_EDGES + NB*EDGE_CAP*4)       // NB*32*16384*4 = 4.2 MB

// scal per batch (8 ints): [0]=doneReduce [2]=kthr(T<<16) [5]=edgeCount
//                          [6]=totalCand  [7]=doneIou

// K1: per-block private LDS histogram -> private global row. Block 0 of each
// batch zeroes the done-counters used by K2/K5 (stream-ordered, race-free).
__global__ __launch_bounds__(1024) void hist_kernel(const float4* __restrict__ probs4,
                                                    unsigned* __restrict__ hrows,
                                                    int* __restrict__ scal) {
    __shared__ unsigned lh[HBINS];
    int t = threadIdx.x;
    for (int j = t; j < HBINS; j += 1024) lh[j] = 0u;
    int b   = blockIdx.x / HB_BLOCKS_PER_B;
    int blk = blockIdx.x % HB_BLOCKS_PER_B;
    if (blk == 0 && t == 0) { scal[b * 8 + 0] = 0; scal[b * 8 + 7] = 0; }
    __syncthreads();
    // float4 = 2 (prob0, prob1) pairs; keys are .y and .w
    const float4* p = probs4 + ((size_t)b * N_ANCHORS + (size_t)blk * HB_CHUNK) / 2;
    #pragma unroll
    for (int k = 0; k < HB_CHUNK / 2048; ++k) {     // 4 iters
        float4 v = p[k * 1024 + t];
        unsigned bin0 = __float_as_uint(v.y) >> 16;
        unsigned bin1 = __float_as_uint(v.w) >> 16;
        if (bin0 > HBINS - 1) bin0 = HBINS - 1;
        if (bin1 > HBINS - 1) bin1 = HBINS - 1;
        atomicAdd(&lh[bin0], 1u);
        atomicAdd(&lh[bin1], 1u);
    }
    __syncthreads();
    unsigned* row = hrows + (size_t)(b * HB_BLOCKS_PER_B + blk) * HBINS;
    for (int j = t; j < HBINS; j += 1024) row[j] = lh[j];
}

// K2: row reduce (16 blocks/batch, 1 bin/thread, coalesced) + per-batch
// LAST BLOCK (16-deep counter chain: harmless) runs threshold-select +
// suffix array + binCnt/edgeCnt zeroing.
__global__ __launch_bounds__(1024) void reduce_scan(const unsigned* __restrict__ hrows,
                                                    unsigned* __restrict__ hist,
                                                    int* __restrict__ scal,
                                                    unsigned* __restrict__ suff,
                                                    unsigned* __restrict__ binCnt) {
    int t = threadIdx.x;
    int b   = blockIdx.x / HR_BLOCKS_PER_B;
    int blk = blockIdx.x % HR_BLOCKS_PER_B;
    int bin = blk * 1024 + t;
    const unsigned* base = hrows + (size_t)b * HB_BLOCKS_PER_B * HBINS + bin;
    unsigned s0 = 0;
    #pragma unroll
    for (int r = 0; r < HB_BLOCKS_PER_B; ++r) s0 += base[(size_t)r * HBINS];
    hist[(size_t)b * HBINS + bin] = s0;
    __shared__ int amLast;
    __syncthreads();
    if (t == 0) {
        __threadfence();
        amLast = (atomicAdd(&scal[b * 8 + 0], 1) == HR_BLOCKS_PER_B - 1);
    }
    __syncthreads();
    if (!amLast) return;
    __threadfence();
    // ---- scan body (1024 threads, 16 bins each) ----
    const unsigned* h = hist + (size_t)b * HBINS;
    unsigned* sf = suff + (size_t)b * HBINS;
    unsigned* bc = binCnt + (size_t)b * HBINS;
    for (int j = t; j < HBINS; j += 1024) bc[j] = 0u;   // zero binCnt (pre-compact)
    if (t == 0) scal[b * 8 + 5] = 0;                    // zero edge counter
    unsigned bbase = t * 16;
    unsigned hl[16];
    unsigned s = 0;
    #pragma unroll
    for (int j = 0; j < 16; ++j) { hl[j] = h[bbase + j]; s += hl[j]; }
    __shared__ unsigned buf[1024];
    buf[t] = s;
    __syncthreads();
    for (int off = 1; off < 1024; off <<= 1) {
        unsigned v = buf[t] + ((t + off < 1024) ? buf[t + off] : 0u);
        __syncthreads();
        buf[t] = v;
        __syncthreads();
    }
    // buf[k] = suffix sum over chunks >= k
    unsigned run = (t < 1023) ? buf[t + 1] : 0u;   // keys in chunks > t
    #pragma unroll
    for (int j = 15; j >= 0; --j) {
        sf[bbase + j] = run;          // strictly-greater-bin count
        run += hl[j];
    }
    unsigned sufInc = buf[t];
    unsigned sufBefore = sufInc - s;
    if (sufBefore < PRE_NMS && sufInc >= PRE_NMS) {   // unique crossing thread
        unsigned r2 = sufBefore;
        unsigned T = 0, totC = 0;
        for (int j = 15; j >= 0; --j) {
            if (r2 + hl[j] >= PRE_NMS) { T = bbase + j; totC = r2 + hl[j]; break; }
            r2 += hl[j];
        }
        if (totC > CAND_CAP) totC = CAND_CAP;
        scal[b * 8 + 2] = (int)(T << 16);   // compact threshold
        scal[b * 8 + 6] = (int)totC;        // total candidates (cand[0..totC) valid)
    }
}

// K3: windowed LDS-privatized compaction (unchanged).
__global__ __launch_bounds__(256) void compact(const float4* __restrict__ probs4,
                                               const int* __restrict__ scal,
                                               const unsigned* __restrict__ suff,
                                               unsigned* __restrict__ binCnt,
                                               u64* __restrict__ cand) {
    __shared__ unsigned lcnt[WINDOW];    // pass A: local count; pass B: global base
    __shared__ u64 keyBuf[CBUF];
    __shared__ unsigned slotBuf[CBUF];
    __shared__ int nc;
    int t = threadIdx.x;
    int b   = blockIdx.x / CB_BLOCKS_PER_B;
    int blk = blockIdx.x % CB_BLOCKS_PER_B;
    for (int j = t; j < WINDOW; j += 256) lcnt[j] = 0u;
    if (t == 0) nc = 0;
    __syncthreads();
    unsigned kthr = (unsigned)scal[b * 8 + 2];
    unsigned T = kthr >> 16;
    const unsigned* sfB = suff + (size_t)b * HBINS;
    unsigned* bcB = binCnt + (size_t)b * HBINS;
    u64* candB = cand + (size_t)b * CAND_CAP;
    size_t anchor0 = (size_t)blk * CB_CHUNK;
    const float4* p = probs4 + ((size_t)b * N_ANCHORS + anchor0) / 2;
    #pragma unroll 2
    for (int k = 0; k < CB_CHUNK / 512; ++k) {
        float4 v = p[k * 256 + t];
        unsigned n0 = (unsigned)(anchor0 + ((size_t)(k * 256 + t)) * 2);
        unsigned keys[2] = { __float_as_uint(v.y), __float_as_uint(v.w) };
        #pragma unroll
        for (int e = 0; e < 2; ++e) {
            unsigned key = keys[e];
            if (key >= kthr) {
                unsigned bin = key >> 16;
                unsigned rel = bin - T;                   // key>=kthr -> bin>=T
                u64 k64 = ((u64)key << 32) | (u64)(~(n0 + e));
                int idx;
                if (rel < WINDOW && (idx = atomicAdd(&nc, 1)) < CBUF) {
                    unsigned slot = atomicAdd(&lcnt[rel], 1u);
                    keyBuf[idx] = k64;
                    slotBuf[idx] = slot;
                } else {   // overflow fallback: direct global allocation (correct, slow)
                    unsigned gs = atomicAdd(&bcB[bin], 1u);
                    unsigned pos = sfB[bin] + gs;
                    if (pos < CAND_CAP) candB[pos] = k64;
                }
            }
        }
    }
    __syncthreads();
    for (int j = t; j < WINDOW; j += 256) {    // pass B: merge, lcnt <- global base
        unsigned c = lcnt[j];
        if (c) lcnt[j] = atomicAdd(&bcB[T + j], c);
    }
    __syncthreads();
    int tot = nc < CBUF ? nc : CBUF;           // pass C: scatter
    for (int k = t; k < tot; k += 256) {
        u64 k64 = keyBuf[k];
        unsigned bin = (unsigned)(k64 >> 48);
        unsigned pos = sfB[bin] + lcnt[bin - T] + slotBuf[k];
        if (pos < CAND_CAP) candB[pos] = k64;
    }
}

// K4: wave-cooperative within-bin ranking + decode (unchanged).
__global__ __launch_bounds__(256) void refine_decode(const u64* __restrict__ cand,
                                                     const int* __restrict__ scal,
                                                     const unsigned* __restrict__ suff,
                                                     const unsigned* __restrict__ binCnt,
                                                     const float* __restrict__ anchors,
                                                     const float* __restrict__ bbox,
                                                     float4* __restrict__ boxes) {
    int b = blockIdx.y;
    int wave = threadIdx.x >> 6;
    int lane = threadIdx.x & 63;
    int p = blockIdx.x * 4 + wave;                     // candidate slot 0..8191
    if (p >= scal[b * 8 + 6]) return;                  // beyond totalCand: stale slot
    u64 my = cand[(size_t)b * CAND_CAP + p];           // wave-uniform broadcast
    unsigned bin = (unsigned)(my >> 48);
    unsigned s = suff[(size_t)b * HBINS + bin];
    if (s >= PRE_NMS) return;                          // entire segment beyond cutoff
    unsigned c = binCnt[(size_t)b * HBINS + bin];
    if (s + c > CAND_CAP) c = CAND_CAP - s;
    const u64* seg = cand + (size_t)b * CAND_CAP + s;
    int cnt = 0;
    for (unsigned q = lane; q < c; q += 64)            // coalesced 512B/iter
        cnt += (seg[q] > my) ? 1 : 0;
    #pragma unroll
    for (int off = 32; off; off >>= 1) cnt += __shfl_down(cnt, off, 64);
    int rank = (int)s + __shfl(cnt, 0, 64);
    if (rank < PRE_NMS && lane == 0) {
        int n = (int)(~(unsigned)(my & 0xFFFFFFFFull));
        const float4* anch4 = (const float4*)anchors + (size_t)b * N_ANCHORS;
        const float4* bb4   = (const float4*)bbox    + (size_t)b * N_ANCHORS;
        float4 a  = anch4[n];
        float4 dd = bb4[n];
        float d0 = dd.x * 0.1f, d1 = dd.y * 0.1f;
        float d2 = dd.z * 0.2f, d3 = dd.w * 0.2f;
        float h = a.z - a.x, w = a.w - a.y;
        float cy = a.x + 0.5f * h + d0 * h;
        float cx = a.y + 0.5f * w + d1 * w;
        h = h * expf(d2);
        w = w * expf(d3);
        float y1 = cy - 0.5f * h, x1 = cx - 0.5f * w;
        float y2 = y1 + h,        x2 = x1 + w;
        y1 = fminf(fmaxf(y1, 0.f), 1.f);
        x1 = fminf(fmaxf(x1, 0.f), 1.f);
        y2 = fminf(fmaxf(y2, 0.f), 1.f);
        x2 = fminf(fmaxf(x2, 0.f), 1.f);
        boxes[(size_t)b * PRE_NMS + rank] = make_float4(y1, x1, y2, x2);
    }
}

// K5: column-owner IoU edges (94 blocks/batch, LDS edge buffer, ONE bulk
// edge-count atomic + ONE completion atomic per block) + last-block fixpoint
// NMS + writeout. Longest same-address chain anywhere: 94.
__global__ __launch_bounds__(512) void iou_nms(const float4* __restrict__ boxes,
                                               int* __restrict__ scal,
                                               unsigned* __restrict__ edges,
                                               float4* __restrict__ out) {
    int c = blockIdx.x;      // column chunk 0..93 (this block OWNS these 64 cols)
    int b = blockIdx.y;
    int t = threadIdx.x;
    const float4* bx = boxes + (size_t)b * PRE_NMS;
    unsigned* egB = edges + (size_t)b * EDGE_CAP;
    __shared__ float4 cb[64];
    __shared__ float  ca[64];
    __shared__ unsigned ebuf[EBUF];
    __shared__ int ne, ebase, amLast;
    if (t == 0) ne = 0;
    if (t < 64) {
        int col = c * 64 + t;
        float4 v = (col < PRE_NMS) ? bx[col] : make_float4(2.f, 2.f, 2.f, 2.f);
        cb[t] = v;
        ca[t] = (v.z - v.x) * (v.w - v.y);
    }
    __syncthreads();
    int rowEnd = (c + 1) * 64; if (rowEnd > PRE_NMS) rowEnd = PRE_NMS;
    for (int i = t; i < rowEnd; i += 512) {            // coalesced row stream
        int rel = i - c * 64;
        u64 maskGT = (rel < 0) ? ~0ull : ((rel >= 63) ? 0ull : ~((2ull << rel) - 1ull));
        if (!maskGT) continue;
        float4 bi = bx[i];
        float ai = (bi.z - bi.x) * (bi.w - bi.y);
        u64 m = 0ull;
        #pragma unroll
        for (int j = 0; j < 64; ++j) {
            float4 bj = cb[j];
            float iy1 = fmaxf(bi.x, bj.x);
            float ix1 = fmaxf(bi.y, bj.y);
            float iy2 = fminf(bi.z, bj.z);
            float ix2 = fminf(bi.w, bj.w);
            float inter = fmaxf(iy2 - iy1, 0.f) * fmaxf(ix2 - ix1, 0.f);
            float uni = ai + ca[j] - inter;
            // iou>0.7 <=> inter>0.7*uni (uni>=0; uni==0 -> inter==0 -> false)
            if (inter > 0.7f * uni) m |= (1ull << j);
        }
        m &= maskGT;
        while (m) {                                    // rare (~600 total edges)
            int j = __ffsll((long long)m) - 1;
            m &= m - 1;
            unsigned e = ((unsigned)(c * 64 + j) << 16) | (unsigned)i;
            int idx = atomicAdd(&ne, 1);               // LDS atomic: cheap
            if (idx < EBUF) ebuf[idx] = e;
            else {                                     // overflow fallback (correct)
                int pos = atomicAdd(&scal[b * 8 + 5], 1);
                if (pos < EDGE_CAP) egB[pos] = e;
            }
        }
    }
    __syncthreads();
    int cntE = ne < EBUF ? ne : EBUF;
    if (t == 0 && cntE > 0) ebase = atomicAdd(&scal[b * 8 + 5], cntE);  // 1/block
    __syncthreads();
    for (int k = t; k < cntE; k += 512) {
        int pos = ebase + k;
        if (pos < EDGE_CAP) egB[pos] = ebuf[k];
    }
    // ---- completion counting: chain depth 94 per batch ----
    __syncthreads();
    if (t == 0) {
        __threadfence();
        amLast = (atomicAdd(&scal[b * 8 + 7], 1) == IOU_BLOCKS_PER_B - 1);
    }
    __syncthreads();
    if (!amLast) return;
    __threadfence();
    // ---- greedy NMS as fixpoint (edges forward i<j -> unique fixpoint) ----
    int E = scal[b * 8 + 5];
    if (E > EDGE_CAP) E = EDGE_CAP;
    __shared__ u64 S[NCHUNK];
    __shared__ u64 Snew[NCHUNK];
    __shared__ int changed;
    __shared__ int pref[NCHUNK];
    __shared__ int totalKept;
    bool staged = (E <= EBUF);
    if (staged) for (int k = t; k < E; k += 512) ebuf[k] = egB[k];  // reuse ebuf
    for (int w = t; w < NCHUNK; w += 512) S[w] = 0ull;
    __syncthreads();
    if (E > 0) {
        for (int it = 0; it < PRE_NMS + 1; ++it) {
            for (int w = t; w < NCHUNK; w += 512) Snew[w] = 0ull;
            if (t == 0) changed = 0;
            __syncthreads();
            for (int k = t; k < E; k += 512) {
                unsigned e = staged ? ebuf[k] : egB[k];
                int i = (int)(e & 0xFFFFu), j = (int)(e >> 16);
                if (!((S[i >> 6] >> (i & 63)) & 1ull))
                    atomicOr(&Snew[j >> 6], 1ull << (j & 63));
            }
            __syncthreads();
            int ch = 0;
            for (int w = t; w < NCHUNK; w += 512) {
                if (Snew[w] != S[w]) { ch = 1; S[w] = Snew[w]; }
            }
            if (ch) changed = 1;
            __syncthreads();
            if (!changed) break;
        }
    }
    for (int w = t; w < NCHUNK; w += 512) {
        u64 valid = (w < NCHUNK - 1) ? ~0ull : ((1ull << (PRE_NMS - (NCHUNK - 1) * 64)) - 1ull);
        Snew[w] = (~S[w]) & valid;            // keep bitset
    }
    __syncthreads();
    if (t == 0) {
        int run = 0;
        for (int w = 0; w < NCHUNK; ++w) { pref[w] = run; run += __popcll(Snew[w]); }
        totalKept = (run < PROPOSALS) ? run : PROPOSALS;
    }
    __syncthreads();
    float4* ob = out + (size_t)b * PROPOSALS;
    if (t < NCHUNK) {
        u64 k = Snew[t];
        int pos = pref[t];
        while (k && pos < PROPOSALS) {
            int l = __ffsll((long long)k) - 1;
            k &= k - 1;
            ob[pos++] = bx[t * 64 + l];
        }
    }
    int tk = totalKept;
    for (int q = tk + t; q < PROPOSALS; q += 512)
        ob[q] = make_float4(0.f, 0.f, 0.f, 0.f);
}

extern "C" void kernel_launch(void* const* d_in, const int* in_sizes, int n_in,
                              void* d_out, int out_size, void* d_ws, size_t ws_size,
                              hipStream_t stream) {
    (void)in_sizes; (void)n_in; (void)out_size; (void)ws_size;
    const float4* probs4 = (const float4*)d_in[0];
    const float* bbox    = (const float*)d_in[1];
    const float* anchors = (const float*)d_in[2];
    char* ws = (char*)d_ws;
    unsigned* hist   = (unsigned*)(ws + OFF_HIST);
    unsigned* binCnt = (unsigned*)(ws + OFF_BCNT);
    int* scal        = (int*)(ws + OFF_SCAL);
    u64* cand        = (u64*)(ws + OFF_CAND);
    unsigned* suff   = (unsigned*)(ws + OFF_SUFF);
    float4* boxes    = (float4*)(ws + OFF_BOXES);
    unsigned* edges  = (unsigned*)(ws + OFF_EDGES);
    unsigned* hrows  = (unsigned*)(ws + OFF_HROWS);

    hist_kernel<<<NB * HB_BLOCKS_PER_B, 1024, 0, stream>>>(probs4, hrows, scal);
    reduce_scan<<<NB * HR_BLOCKS_PER_B, 1024, 0, stream>>>(hrows, hist, scal, suff, binCnt);
    compact<<<NB * CB_BLOCKS_PER_B, 256, 0, stream>>>(probs4, scal, suff, binCnt, cand);
    refine_decode<<<dim3(CAND_CAP / 4, NB), 256, 0, stream>>>(cand, scal, suff, binCnt,
                                                              anchors, bbox, boxes);
    iou_nms<<<dim3(NCHUNK, NB), 512, 0, stream>>>(boxes, scal, edges, (float4*)d_out);
}

// Round 12
// 83.953 us; speedup vs baseline: 2.0036x; 2.0036x over previous
//
#include <hip/hip_runtime.h>
#include <stdint.h>

typedef unsigned long long u64;

#define NB 2
#define N_ANCHORS 262144           // 2^18
#define PRE_NMS 6000
#define PROPOSALS 2000
#define NCHUNK 94                  // ceil(6000/64) words in keep/suppress bitset
#define CAND_CAP 8192
#define HBINS 16384                // scores in (0,1) -> key>>16 <= 0x3F80 < 16384
#define HB_BLOCKS_PER_B 32
#define HB_CHUNK (N_ANCHORS / HB_BLOCKS_PER_B)   // 8192
#define HR_BLOCKS_PER_B 16         // reduce blocks per batch (1024 bins each)
#define CB_BLOCKS_PER_B 64
#define CB_CHUNK (N_ANCHORS / CB_BLOCKS_PER_B)   // 4096
#define CBUF 512
#define WINDOW 2048                // candidate bins span ~17 bins here; 2048 is ample
#define EDGE_CAP 65536             // overflow-tail capacity (cold path)
#define IOU_RB ((PRE_NMS + 255) / 256)           // 24 row blocks
#define NTILES (NCHUNK * IOU_RB)                 // 94*24 = 2256
#define ESLOT_CAP 64               // per-tile private edge slots (~600 edges total)
#define EBUF_FIX 8192              // nms_fix LDS edge buffer

// ---- workspace layout (bytes) ---- no pre-zero kernel: hrows/hist/suff fully
// overwritten; doneReduce zeroed by K1; binCnt+overflowCnt zeroed by K2-lastblock;
// cand guarded by totalCand; boxes ranks [0,6000) all written; ecnt written by
// every tile block; eslot guarded by ecnt; edges tail guarded by overflowCnt.
#define OFF_HIST 0                                  // 131072
#define OFF_BCNT (NB*HBINS*4)                       // 131072
#define OFF_SCAL (2*NB*HBINS*4)                     // 256
#define OFF_CAND (OFF_SCAL + 256)                   // 131072
#define OFF_SUFF (OFF_CAND + NB*CAND_CAP*8)         // 131072
#define OFF_BOXES (OFF_SUFF + NB*HBINS*4)           // 192000
#define OFF_EDGES (OFF_BOXES + NB*PRE_NMS*16)       // 524288 (overflow tail)
#define OFF_ECNT (OFF_EDGES + NB*EDGE_CAP*4)        // NB*2256*4 = 18048
#define OFF_ESLOT (OFF_ECNT + NB*NTILES*4)          // NB*2256*64*4 = 1155072
#define OFF_HROWS (OFF_ESLOT + (size_t)NB*NTILES*ESLOT_CAP*4)  // NB*32*16384*4 = 4.2 MB

// scal per batch (8 ints): [0]=doneReduce [2]=kthr(T<<16) [5]=edgeOverflowCnt
//                          [6]=totalCand

// K1: per-block private LDS histogram -> private global row. Block 0 of each
// batch zeroes the doneReduce counter (stream-ordered before K2 uses it).
__global__ __launch_bounds__(1024) void hist_kernel(const float4* __restrict__ probs4,
                                                    unsigned* __restrict__ hrows,
                                                    int* __restrict__ scal) {
    __shared__ unsigned lh[HBINS];
    int t = threadIdx.x;
    for (int j = t; j < HBINS; j += 1024) lh[j] = 0u;
    int b   = blockIdx.x / HB_BLOCKS_PER_B;
    int blk = blockIdx.x % HB_BLOCKS_PER_B;
    if (blk == 0 && t == 0) scal[b * 8 + 0] = 0;
    __syncthreads();
    // float4 = 2 (prob0, prob1) pairs; keys are .y and .w
    const float4* p = probs4 + ((size_t)b * N_ANCHORS + (size_t)blk * HB_CHUNK) / 2;
    #pragma unroll
    for (int k = 0; k < HB_CHUNK / 2048; ++k) {     // 4 iters
        float4 v = p[k * 1024 + t];
        unsigned bin0 = __float_as_uint(v.y) >> 16;
        unsigned bin1 = __float_as_uint(v.w) >> 16;
        if (bin0 > HBINS - 1) bin0 = HBINS - 1;
        if (bin1 > HBINS - 1) bin1 = HBINS - 1;
        atomicAdd(&lh[bin0], 1u);
        atomicAdd(&lh[bin1], 1u);
    }
    __syncthreads();
    unsigned* row = hrows + (size_t)(b * HB_BLOCKS_PER_B + blk) * HBINS;
    for (int j = t; j < HBINS; j += 1024) row[j] = lh[j];
}

// K2: row reduce (16 blocks/batch, 1 bin/thread, coalesced) + per-batch
// LAST BLOCK (16-deep counter chain: harmless) runs threshold-select +
// suffix array + binCnt/overflowCnt zeroing.
__global__ __launch_bounds__(1024) void reduce_scan(const unsigned* __restrict__ hrows,
                                                    unsigned* __restrict__ hist,
                                                    int* __restrict__ scal,
                                                    unsigned* __restrict__ suff,
                                                    unsigned* __restrict__ binCnt) {
    int t = threadIdx.x;
    int b   = blockIdx.x / HR_BLOCKS_PER_B;
    int blk = blockIdx.x % HR_BLOCKS_PER_B;
    int bin = blk * 1024 + t;
    const unsigned* base = hrows + (size_t)b * HB_BLOCKS_PER_B * HBINS + bin;
    unsigned s0 = 0;
    #pragma unroll
    for (int r = 0; r < HB_BLOCKS_PER_B; ++r) s0 += base[(size_t)r * HBINS];
    hist[(size_t)b * HBINS + bin] = s0;
    __shared__ int amLast;
    __syncthreads();
    if (t == 0) {
        __threadfence();
        amLast = (atomicAdd(&scal[b * 8 + 0], 1) == HR_BLOCKS_PER_B - 1);
    }
    __syncthreads();
    if (!amLast) return;
    __threadfence();
    // ---- scan body (1024 threads, 16 bins each) ----
    const unsigned* h = hist + (size_t)b * HBINS;
    unsigned* sf = suff + (size_t)b * HBINS;
    unsigned* bc = binCnt + (size_t)b * HBINS;
    for (int j = t; j < HBINS; j += 1024) bc[j] = 0u;   // zero binCnt (pre-compact)
    if (t == 0) scal[b * 8 + 5] = 0;                    // zero edge overflow counter
    unsigned bbase = t * 16;
    unsigned hl[16];
    unsigned s = 0;
    #pragma unroll
    for (int j = 0; j < 16; ++j) { hl[j] = h[bbase + j]; s += hl[j]; }
    __shared__ unsigned buf[1024];
    buf[t] = s;
    __syncthreads();
    for (int off = 1; off < 1024; off <<= 1) {
        unsigned v = buf[t] + ((t + off < 1024) ? buf[t + off] : 0u);
        __syncthreads();
        buf[t] = v;
        __syncthreads();
    }
    // buf[k] = suffix sum over chunks >= k
    unsigned run = (t < 1023) ? buf[t + 1] : 0u;   // keys in chunks > t
    #pragma unroll
    for (int j = 15; j >= 0; --j) {
        sf[bbase + j] = run;          // strictly-greater-bin count
        run += hl[j];
    }
    unsigned sufInc = buf[t];
    unsigned sufBefore = sufInc - s;
    if (sufBefore < PRE_NMS && sufInc >= PRE_NMS) {   // unique crossing thread
        unsigned r2 = sufBefore;
        unsigned T = 0, totC = 0;
        for (int j = 15; j >= 0; --j) {
            if (r2 + hl[j] >= PRE_NMS) { T = bbase + j; totC = r2 + hl[j]; break; }
            r2 += hl[j];
        }
        if (totC > CAND_CAP) totC = CAND_CAP;
        scal[b * 8 + 2] = (int)(T << 16);   // compact threshold
        scal[b * 8 + 6] = (int)totC;        // total candidates (cand[0..totC) valid)
    }
}

// K3: windowed LDS-privatized compaction (unchanged, measured good).
__global__ __launch_bounds__(256) void compact(const float4* __restrict__ probs4,
                                               const int* __restrict__ scal,
                                               const unsigned* __restrict__ suff,
                                               unsigned* __restrict__ binCnt,
                                               u64* __restrict__ cand) {
    __shared__ unsigned lcnt[WINDOW];    // pass A: local count; pass B: global base
    __shared__ u64 keyBuf[CBUF];
    __shared__ unsigned slotBuf[CBUF];
    __shared__ int nc;
    int t = threadIdx.x;
    int b   = blockIdx.x / CB_BLOCKS_PER_B;
    int blk = blockIdx.x % CB_BLOCKS_PER_B;
    for (int j = t; j < WINDOW; j += 256) lcnt[j] = 0u;
    if (t == 0) nc = 0;
    __syncthreads();
    unsigned kthr = (unsigned)scal[b * 8 + 2];
    unsigned T = kthr >> 16;
    const unsigned* sfB = suff + (size_t)b * HBINS;
    unsigned* bcB = binCnt + (size_t)b * HBINS;
    u64* candB = cand + (size_t)b * CAND_CAP;
    size_t anchor0 = (size_t)blk * CB_CHUNK;
    const float4* p = probs4 + ((size_t)b * N_ANCHORS + anchor0) / 2;
    #pragma unroll 2
    for (int k = 0; k < CB_CHUNK / 512; ++k) {
        float4 v = p[k * 256 + t];
        unsigned n0 = (unsigned)(anchor0 + ((size_t)(k * 256 + t)) * 2);
        unsigned keys[2] = { __float_as_uint(v.y), __float_as_uint(v.w) };
        #pragma unroll
        for (int e = 0; e < 2; ++e) {
            unsigned key = keys[e];
            if (key >= kthr) {
                unsigned bin = key >> 16;
                unsigned rel = bin - T;                   // key>=kthr -> bin>=T
                u64 k64 = ((u64)key << 32) | (u64)(~(n0 + e));
                int idx;
                if (rel < WINDOW && (idx = atomicAdd(&nc, 1)) < CBUF) {
                    unsigned slot = atomicAdd(&lcnt[rel], 1u);
                    keyBuf[idx] = k64;
                    slotBuf[idx] = slot;
                } else {   // overflow fallback: direct global allocation (correct, slow)
                    unsigned gs = atomicAdd(&bcB[bin], 1u);
                    unsigned pos = sfB[bin] + gs;
                    if (pos < CAND_CAP) candB[pos] = k64;
                }
            }
        }
    }
    __syncthreads();
    for (int j = t; j < WINDOW; j += 256) {    // pass B: merge, lcnt <- global base
        unsigned c = lcnt[j];
        if (c) lcnt[j] = atomicAdd(&bcB[T + j], c);
    }
    __syncthreads();
    int tot = nc < CBUF ? nc : CBUF;           // pass C: scatter
    for (int k = t; k < tot; k += 256) {
        u64 k64 = keyBuf[k];
        unsigned bin = (unsigned)(k64 >> 48);
        unsigned pos = sfB[bin] + lcnt[bin - T] + slotBuf[k];
        if (pos < CAND_CAP) candB[pos] = k64;
    }
}

// K4: wave-cooperative within-bin ranking + decode (unchanged, measured good).
__global__ __launch_bounds__(256) void refine_decode(const u64* __restrict__ cand,
                                                     const int* __restrict__ scal,
                                                     const unsigned* __restrict__ suff,
                                                     const unsigned* __restrict__ binCnt,
                                                     const float* __restrict__ anchors,
                                                     const float* __restrict__ bbox,
                                                     float4* __restrict__ boxes) {
    int b = blockIdx.y;
    int wave = threadIdx.x >> 6;
    int lane = threadIdx.x & 63;
    int p = blockIdx.x * 4 + wave;                     // candidate slot 0..8191
    if (p >= scal[b * 8 + 6]) return;                  // beyond totalCand: stale slot
    u64 my = cand[(size_t)b * CAND_CAP + p];           // wave-uniform broadcast
    unsigned bin = (unsigned)(my >> 48);
    unsigned s = suff[(size_t)b * HBINS + bin];
    if (s >= PRE_NMS) return;                          // entire segment beyond cutoff
    unsigned c = binCnt[(size_t)b * HBINS + bin];
    if (s + c > CAND_CAP) c = CAND_CAP - s;
    const u64* seg = cand + (size_t)b * CAND_CAP + s;
    int cnt = 0;
    for (unsigned q = lane; q < c; q += 64)            // coalesced 512B/iter
        cnt += (seg[q] > my) ? 1 : 0;
    #pragma unroll
    for (int off = 32; off; off >>= 1) cnt += __shfl_down(cnt, off, 64);
    int rank = (int)s + __shfl(cnt, 0, 64);
    if (rank < PRE_NMS && lane == 0) {
        int n = (int)(~(unsigned)(my & 0xFFFFFFFFull));
        const float4* anch4 = (const float4*)anchors + (size_t)b * N_ANCHORS;
        const float4* bb4   = (const float4*)bbox    + (size_t)b * N_ANCHORS;
        float4 a  = anch4[n];
        float4 dd = bb4[n];
        float d0 = dd.x * 0.1f, d1 = dd.y * 0.1f;
        float d2 = dd.z * 0.2f, d3 = dd.w * 0.2f;
        float h = a.z - a.x, w = a.w - a.y;
        float cy = a.x + 0.5f * h + d0 * h;
        float cx = a.y + 0.5f * w + d1 * w;
        h = h * expf(d2);
        w = w * expf(d3);
        float y1 = cy - 0.5f * h, x1 = cx - 0.5f * w;
        float y2 = y1 + h,        x2 = x1 + w;
        y1 = fminf(fmaxf(y1, 0.f), 1.f);
        x1 = fminf(fmaxf(x1, 0.f), 1.f);
        y2 = fminf(fmaxf(y2, 0.f), 1.f);
        x2 = fminf(fmaxf(x2, 0.f), 1.f);
        boxes[(size_t)b * PRE_NMS + rank] = make_float4(y1, x1, y2, x2);
    }
}

// K5: sparse IoU edges, R9 tile shape (256 thr, small body -> no spill), but
// edges go to PER-TILE private slots: zero global atomics on the common path.
__global__ __launch_bounds__(256) void iou_edges(const float4* __restrict__ boxes,
                                                 int* __restrict__ scal,
                                                 unsigned* __restrict__ edges,
                                                 int* __restrict__ ecnt,
                                                 unsigned* __restrict__ eslot) {
    int c  = blockIdx.x;     // column chunk 0..93
    int rb = blockIdx.y;     // row block 0..23
    int b  = blockIdx.z;
    int t  = threadIdx.x;
    int lin = c * IOU_RB + rb;
    int rowBase = rb * 256;
    if (rowBase >= (c + 1) * 64) {           // fully below diagonal: no i<j pairs
        if (t == 0) ecnt[b * NTILES + lin] = 0;
        return;
    }
    const float4* bx = boxes + (size_t)b * PRE_NMS;
    __shared__ float4 cb[64];
    __shared__ float  ca[64];
    __shared__ unsigned lbuf[ESLOT_CAP];
    __shared__ int ne;
    if (t == 0) ne = 0;
    if (t < 64) {
        int col = c * 64 + t;
        float4 v = (col < PRE_NMS) ? bx[col] : make_float4(2.f, 2.f, 2.f, 2.f);
        cb[t] = v;
        ca[t] = (v.z - v.x) * (v.w - v.y);
    }
    __syncthreads();
    int i = rowBase + t;
    if (i < PRE_NMS) {
        int rel = i - c * 64;
        u64 maskGT = (rel < 0) ? ~0ull : ((rel >= 63) ? 0ull : ~((2ull << rel) - 1ull));
        if (maskGT) {
            float4 bi = bx[i];
            float ai = (bi.z - bi.x) * (bi.w - bi.y);
            u64 m = 0ull;
            #pragma unroll
            for (int j = 0; j < 64; ++j) {
                float4 bj = cb[j];
                float iy1 = fmaxf(bi.x, bj.x);
                float ix1 = fmaxf(bi.y, bj.y);
                float iy2 = fminf(bi.z, bj.z);
                float ix2 = fminf(bi.w, bj.w);
                float inter = fmaxf(iy2 - iy1, 0.f) * fmaxf(ix2 - ix1, 0.f);
                float uni = ai + ca[j] - inter;
                // iou>0.7 <=> inter>0.7*uni (uni>=0; uni==0 -> inter==0 -> false)
                if (inter > 0.7f * uni) m |= (1ull << j);
            }
            m &= maskGT;
            while (m) {                               // rare (~600 edges total)
                int j = __ffsll((long long)m) - 1;
                m &= m - 1;
                unsigned e = ((unsigned)(c * 64 + j) << 16) | (unsigned)i;
                int idx = atomicAdd(&ne, 1);          // LDS atomic: cheap
                if (idx < ESLOT_CAP) lbuf[idx] = e;
                else {                                // cold overflow: global tail
                    int pos = atomicAdd(&scal[b * 8 + 5], 1);
                    if (pos < EDGE_CAP) edges[(size_t)b * EDGE_CAP + pos] = e;
                }
            }
        }
    }
    __syncthreads();
    int cnt = ne < ESLOT_CAP ? ne : ESLOT_CAP;
    if (t == 0) ecnt[b * NTILES + lin] = cnt;
    if (t < cnt) eslot[((size_t)b * NTILES + lin) * ESLOT_CAP + t] = lbuf[t];
}

// K6: gather edges from slots (+ overflow tail) into LDS, run exact greedy-NMS
// fixpoint (edges forward i<j -> unique fixpoint = greedy), write output.
__global__ __launch_bounds__(256) void nms_fix(const int* __restrict__ ecnt,
                                               const unsigned* __restrict__ eslot,
                                               const unsigned* __restrict__ edges,
                                               const int* __restrict__ scal,
                                               const float4* __restrict__ boxes,
                                               float4* __restrict__ out) {
    int b = blockIdx.x;
    int t = threadIdx.x;
    __shared__ unsigned ebufL[EBUF_FIX];
    __shared__ int neL;
    __shared__ u64 S[NCHUNK];
    __shared__ u64 Snew[NCHUNK];
    __shared__ int changed;
    __shared__ int pref[NCHUNK];
    __shared__ int totalKept;
    if (t == 0) neL = 0;
    __syncthreads();
    for (int lin = t; lin < NTILES; lin += 256) {      // coalesced count reads
        int c = ecnt[b * NTILES + lin];
        const unsigned* sl = eslot + ((size_t)b * NTILES + lin) * ESLOT_CAP;
        for (int k = 0; k < c; ++k) {
            int idx = atomicAdd(&neL, 1);
            if (idx < EBUF_FIX) ebufL[idx] = sl[k];
        }
    }
    int ov = scal[b * 8 + 5];
    if (ov > EDGE_CAP) ov = EDGE_CAP;
    for (int k = t; k < ov; k += 256) {                // cold path (ov==0 here)
        int idx = atomicAdd(&neL, 1);
        if (idx < EBUF_FIX) ebufL[idx] = edges[(size_t)b * EDGE_CAP + k];
    }
    for (int w = t; w < NCHUNK; w += 256) S[w] = 0ull;
    __syncthreads();
    int E = neL < EBUF_FIX ? neL : EBUF_FIX;
    if (E > 0) {
        for (int it = 0; it < PRE_NMS + 1; ++it) {
            for (int w = t; w < NCHUNK; w += 256) Snew[w] = 0ull;
            if (t == 0) changed = 0;
            __syncthreads();
            for (int k = t; k < E; k += 256) {
                unsigned e = ebufL[k];
                int i = (int)(e & 0xFFFFu), j = (int)(e >> 16);
                if (!((S[i >> 6] >> (i & 63)) & 1ull))
                    atomicOr(&Snew[j >> 6], 1ull << (j & 63));
            }
            __syncthreads();
            int ch = 0;
            for (int w = t; w < NCHUNK; w += 256) {
                if (Snew[w] != S[w]) { ch = 1; S[w] = Snew[w]; }
            }
            if (ch) changed = 1;
            __syncthreads();
            if (!changed) break;
        }
    }
    for (int w = t; w < NCHUNK; w += 256) {
        u64 valid = (w < NCHUNK - 1) ? ~0ull : ((1ull << (PRE_NMS - (NCHUNK - 1) * 64)) - 1ull);
        Snew[w] = (~S[w]) & valid;            // keep bitset
    }
    __syncthreads();
    if (t == 0) {
        int run = 0;
        for (int w = 0; w < NCHUNK; ++w) { pref[w] = run; run += __popcll(Snew[w]); }
        totalKept = (run < PROPOSALS) ? run : PROPOSALS;
    }
    __syncthreads();
    const float4* bx = boxes + (size_t)b * PRE_NMS;
    float4* ob = out + (size_t)b * PROPOSALS;
    if (t < NCHUNK) {
        u64 k = Snew[t];
        int pos = pref[t];
        while (k && pos < PROPOSALS) {
            int l = __ffsll((long long)k) - 1;
            k &= k - 1;
            ob[pos++] = bx[t * 64 + l];
        }
    }
    int tk = totalKept;
    for (int q = tk + t; q < PROPOSALS; q += 256)
        ob[q] = make_float4(0.f, 0.f, 0.f, 0.f);
}

extern "C" void kernel_launch(void* const* d_in, const int* in_sizes, int n_in,
                              void* d_out, int out_size, void* d_ws, size_t ws_size,
                              hipStream_t stream) {
    (void)in_sizes; (void)n_in; (void)out_size; (void)ws_size;
    const float4* probs4 = (const float4*)d_in[0];
    const float* bbox    = (const float*)d_in[1];
    const float* anchors = (const float*)d_in[2];
    char* ws = (char*)d_ws;
    unsigned* hist   = (unsigned*)(ws + OFF_HIST);
    unsigned* binCnt = (unsigned*)(ws + OFF_BCNT);
    int* scal        = (int*)(ws + OFF_SCAL);
    u64* cand        = (u64*)(ws + OFF_CAND);
    unsigned* suff   = (unsigned*)(ws + OFF_SUFF);
    float4* boxes    = (float4*)(ws + OFF_BOXES);
    unsigned* edges  = (unsigned*)(ws + OFF_EDGES);
    int* ecnt        = (int*)(ws + OFF_ECNT);
    unsigned* eslot  = (unsigned*)(ws + OFF_ESLOT);
    unsigned* hrows  = (unsigned*)(ws + OFF_HROWS);

    hist_kernel<<<NB * HB_BLOCKS_PER_B, 1024, 0, stream>>>(probs4, hrows, scal);
    reduce_scan<<<NB * HR_BLOCKS_PER_B, 1024, 0, stream>>>(hrows, hist, scal, suff, binCnt);
    compact<<<NB * CB_BLOCKS_PER_B, 256, 0, stream>>>(probs4, scal, suff, binCnt, cand);
    refine_decode<<<dim3(CAND_CAP / 4, NB), 256, 0, stream>>>(cand, scal, suff, binCnt,
                                                              anchors, bbox, boxes);
    iou_edges<<<dim3(NCHUNK, IOU_RB, NB), 256, 0, stream>>>(boxes, scal, edges, ecnt, eslot);
    nms_fix<<<NB, 256, 0, stream>>>(ecnt, eslot, edges, scal, boxes, (float4*)d_out);
}